// Round 2
// baseline (230.183 us; speedup 1.0000x reference)
//
#include <hip/hip_runtime.h>
#include <stdint.h>
#include <stddef.h>

// Attention_50886772523162: x[2,2048,1024] -> causal MHA (16 heads, hd=64) -> out
// Input/output dtype (fp32 vs bf16) detected at runtime from bit patterns of x;
// all compute in bf16 MFMA with fp32 accumulation.
// Pipeline: detect -> convert x -> transpose(+convert) weights -> Q proj ->
//           KV proj -> causal flash attn -> O proj (flag-typed output).

typedef __bf16 bf16;
typedef __bf16 bf16x8 __attribute__((ext_vector_type(8)));
typedef __bf16 bf16x2 __attribute__((ext_vector_type(2)));
typedef float  f32x4  __attribute__((ext_vector_type(4)));

#define NSEQ 2048
#define DM   1024
#define HD   64
#define MASKV (-50000.0f)

// ---------------- dtype detection ----------------
// If x is bf16-packed, the LOW 16 bits of each 32-bit word are a bf16 of a
// ~N(0,1) sample: exponent byte in [110,132] essentially always. If x is
// fp32, those bits are low mantissa bits: uniform, in-range ~9% of the time.
__global__ void detect_dtype(const uint32_t* __restrict__ x, int* __restrict__ flag) {
  __shared__ int cnt;
  if (threadIdx.x == 0) cnt = 0;
  __syncthreads();
  int c = 0;
  for (int i = threadIdx.x; i < 4096; i += 256) {
    uint32_t e = (x[i] >> 7) & 0xFF;
    if (e >= 110 && e <= 132) c++;
  }
  atomicAdd(&cnt, c);
  __syncthreads();
  if (threadIdx.x == 0) *flag = (cnt > 2048) ? 1 : 0;   // 1 = bf16 data
}

// ---------------- x -> canonical bf16 ----------------
__global__ __launch_bounds__(256) void convert_x(
    const void* __restrict__ in, bf16* __restrict__ out, int n,
    const int* __restrict__ flagp) {
  const int flag = *flagp;
  const int i = (blockIdx.x * 256 + threadIdx.x) * 8;
  if (i >= n) return;
  if (flag) {
    *(bf16x8*)(out + i) = *(const bf16x8*)((const bf16*)in + i);
  } else {
    const float* f = (const float*)in;
    bf16x8 v;
#pragma unroll
    for (int e = 0; e < 8; ++e) v[e] = (bf16)f[i + e];
    *(bf16x8*)(out + i) = v;
  }
}

// ---------------- weight transpose(+convert): in[K][N] -> out[N][K] ----------------
__global__ void transpose_conv(const void* __restrict__ in, bf16* __restrict__ out,
                               int K, int N, const int* __restrict__ flagp) {
  __shared__ bf16 tile[32][33];
  const int flag = *flagp;
  const int k0 = blockIdx.y * 32, n0 = blockIdx.x * 32;
  const int tx = threadIdx.x, ty = threadIdx.y;
  if (flag) {
    const bf16* p = (const bf16*)in;
#pragma unroll
    for (int i = ty; i < 32; i += 8)
      tile[i][tx] = p[(size_t)(k0 + i) * N + n0 + tx];
  } else {
    const float* p = (const float*)in;
#pragma unroll
    for (int i = ty; i < 32; i += 8)
      tile[i][tx] = (bf16)p[(size_t)(k0 + i) * N + n0 + tx];
  }
  __syncthreads();
#pragma unroll
  for (int i = ty; i < 32; i += 8)
    out[(size_t)(n0 + i) * K + k0 + tx] = tile[tx][i];
}

// ---------------- GEMM: C[M][N] = A[M][K] * Bt[N][K]^T ----------------
// 128x128 tile, BK=64, 4 waves (2x2), mfma_f32_16x16x32_bf16.
// LDS rows XOR-swizzled: byte ^= (row&7)<<4 (kills stride-128B bank conflict).
// Output: flagp==nullptr -> bf16; else *flagp ? bf16 : fp32 (for d_out).
__global__ __launch_bounds__(256) void gemm_bt(
    const bf16* __restrict__ A, const bf16* __restrict__ Bt,
    void* __restrict__ C, int M, int N, int K, const int* flagp)
{
  __shared__ bf16 As[128][64];
  __shared__ bf16 Bs[128][64];
  const int tid  = threadIdx.x;
  const int wave = tid >> 6, lane = tid & 63;
  const int fr = lane & 15, fg = lane >> 4;     // fragment row, k-group
  const int m0 = blockIdx.y * 128, n0 = blockIdx.x * 128;
  const int wr = (wave >> 1) * 64, wc = (wave & 1) * 64;
  const int srow = tid >> 3, sch = tid & 7;     // staging: 32 rows x 8 chunks/pass

  f32x4 acc[4][4] = {};

  for (int kt = 0; kt < K; kt += 64) {
    __syncthreads();
#pragma unroll
    for (int p = 0; p < 4; ++p) {
      const int r = srow + p * 32;
      bf16x8 va = *(const bf16x8*)(A  + (size_t)(m0 + r) * K + kt + sch * 8);
      bf16x8 vb = *(const bf16x8*)(Bt + (size_t)(n0 + r) * K + kt + sch * 8);
      const int lb = (sch * 16) ^ ((r & 7) << 4);
      *(bf16x8*)((char*)&As[r][0] + lb) = va;
      *(bf16x8*)((char*)&Bs[r][0] + lb) = vb;
    }
    __syncthreads();
#pragma unroll
    for (int s = 0; s < 2; ++s) {
      bf16x8 af[4], bfr[4];
#pragma unroll
      for (int i = 0; i < 4; ++i) {
        const int ar = wr + i * 16 + fr;
        af[i]  = *(const bf16x8*)((const char*)&As[ar][0] +
                   ((s * 64 + fg * 16) ^ ((ar & 7) << 4)));
        const int br = wc + i * 16 + fr;
        bfr[i] = *(const bf16x8*)((const char*)&Bs[br][0] +
                   ((s * 64 + fg * 16) ^ ((br & 7) << 4)));
      }
#pragma unroll
      for (int i = 0; i < 4; ++i)
#pragma unroll
        for (int j = 0; j < 4; ++j)
          acc[i][j] = __builtin_amdgcn_mfma_f32_16x16x32_bf16(
              af[i], bfr[j], acc[i][j], 0, 0, 0);
    }
  }
  // C/D layout: col = lane&15, row = (lane>>4)*4 + reg  [m89-verified]
  const int crow = m0 + wr + fg * 4;
  const int ccol = n0 + wc + fr;
  const int as_bf16 = flagp ? *flagp : 1;
  if (as_bf16) {
    bf16* Cb = (bf16*)C;
#pragma unroll
    for (int i = 0; i < 4; ++i)
#pragma unroll
      for (int j = 0; j < 4; ++j)
#pragma unroll
        for (int r = 0; r < 4; ++r)
          Cb[(size_t)(crow + i * 16 + r) * N + ccol + j * 16] = (bf16)acc[i][j][r];
  } else {
    float* Cf = (float*)C;
#pragma unroll
    for (int i = 0; i < 4; ++i)
#pragma unroll
      for (int j = 0; j < 4; ++j)
#pragma unroll
        for (int r = 0; r < 4; ++r)
          Cf[(size_t)(crow + i * 16 + r) * N + ccol + j * 16] = acc[i][j][r];
  }
}

// ---------------- causal flash attention ----------------
// Q: [B][N][DM] (heads interleaved), KV: [B][N][2*DM] (K | V), O: [B][N][DM]
// block = one (b,h,q-tile of 64 rows); 4 waves x 16 q-rows; KV tiles of 64.
__global__ __launch_bounds__(256) void attn_fwd(
    const bf16* __restrict__ Q, const bf16* __restrict__ KV,
    bf16* __restrict__ O)
{
  __shared__ bf16 Ks[64][64];      // K tile, natural [j][d], swizzled rows
  __shared__ bf16 Vt[64][64];      // V tile, transposed [d][j], swizzled rows
  __shared__ bf16 Ps[4][16][64];   // per-wave P (D-layout -> A-layout bridge)

  const int qt = blockIdx.x;       // q tile 0..31
  const int bh = blockIdx.y;       // 0..31
  const int bi = bh >> 4, hi = bh & 15;
  const int tid = threadIdx.x, wave = tid >> 6, lane = tid & 63;
  const int fr = lane & 15, fg = lane >> 4;

  const size_t qbase  = (size_t)bi * NSEQ * DM + (size_t)hi * HD;
  const size_t kvbase = (size_t)bi * NSEQ * (2 * DM) + (size_t)hi * HD;

  // Q fragments (A-operand): row = lane&15 within wave's 16 rows
  bf16x8 qf[2];
  {
    const int qrow = qt * 64 + wave * 16 + fr;
#pragma unroll
    for (int s = 0; s < 2; ++s)
      qf[s] = *(const bf16x8*)(Q + qbase + (size_t)qrow * DM + s * 32 + fg * 8);
  }

  f32x4 oacc[4] = {};
  float mrow[4] = {-1e30f, -1e30f, -1e30f, -1e30f};
  float lrow[4] = {0.f, 0.f, 0.f, 0.f};

  const int sjr = tid >> 3, sjc = tid & 7;              // K staging
  const int vjp = (tid & 31) * 2, vd0 = (tid >> 5) * 8; // V staging (transpose)

  for (int t = 0; t <= qt; ++t) {
    const int j0 = t * 64;
    __syncthreads();
    // stage K tile [64][64]
#pragma unroll
    for (int p = 0; p < 2; ++p) {
      const int j = sjr + p * 32;
      bf16x8 v = *(const bf16x8*)(KV + kvbase + (size_t)(j0 + j) * (2 * DM) + sjc * 8);
      *(bf16x8*)((char*)&Ks[j][0] + ((sjc * 16) ^ ((j & 7) << 4))) = v;
    }
    // stage V tile transposed -> Vt[d][j]
    {
      bf16x8 v0 = *(const bf16x8*)(KV + kvbase + DM + (size_t)(j0 + vjp)     * (2 * DM) + vd0);
      bf16x8 v1 = *(const bf16x8*)(KV + kvbase + DM + (size_t)(j0 + vjp + 1) * (2 * DM) + vd0);
#pragma unroll
      for (int e = 0; e < 8; ++e) {
        const int d = vd0 + e;
        bf16x2 pr; pr[0] = v0[e]; pr[1] = v1[e];
        *(bf16x2*)((char*)&Vt[d][0] + ((vjp * 2) ^ ((d & 7) << 4))) = pr;
      }
    }
    __syncthreads();

    // S = Q K^T  (16 x 64 per wave)
    f32x4 sf[4];
#pragma unroll
    for (int jf = 0; jf < 4; ++jf) {
      f32x4 a = {};
#pragma unroll
      for (int s = 0; s < 2; ++s) {
        const int kr = jf * 16 + fr;
        bf16x8 kf = *(const bf16x8*)((const char*)&Ks[kr][0] +
                     ((s * 64 + fg * 16) ^ ((kr & 7) << 4)));
        a = __builtin_amdgcn_mfma_f32_16x16x32_bf16(qf[s], kf, a, 0, 0, 0);
      }
      sf[jf] = a;
    }
    // scale + causal mask (diagonal tile only; ref uses -50000, not -inf)
    const bool diag = (t == qt);
#pragma unroll
    for (int jf = 0; jf < 4; ++jf)
#pragma unroll
      for (int r = 0; r < 4; ++r) {
        float v = sf[jf][r] * 0.125f;
        if (diag && (j0 + jf * 16 + fr > qt * 64 + wave * 16 + fg * 4 + r))
          v = MASKV;
        sf[jf][r] = v;
      }
    // online softmax (rows live across 16-lane groups; reduce via shfl_xor)
#pragma unroll
    for (int r = 0; r < 4; ++r) {
      float m = fmaxf(fmaxf(sf[0][r], sf[1][r]), fmaxf(sf[2][r], sf[3][r]));
#pragma unroll
      for (int off = 1; off < 16; off <<= 1) m = fmaxf(m, __shfl_xor(m, off));
      const float mnew  = fmaxf(mrow[r], m);
      const float alpha = __expf(mrow[r] - mnew);
      mrow[r] = mnew;
      float ps = 0.f;
#pragma unroll
      for (int jf = 0; jf < 4; ++jf) {
        const float p = __expf(sf[jf][r] - mnew);
        sf[jf][r] = p;
        ps += p;
      }
#pragma unroll
      for (int off = 1; off < 16; off <<= 1) ps += __shfl_xor(ps, off);
      lrow[r] = lrow[r] * alpha + ps;
#pragma unroll
      for (int df = 0; df < 4; ++df) oacc[df][r] *= alpha;
    }
    // P (D-layout) -> per-wave LDS (swizzled) so PV can read A-layout frags
#pragma unroll
    for (int jf = 0; jf < 4; ++jf)
#pragma unroll
      for (int r = 0; r < 4; ++r) {
        const int ii = fg * 4 + r, jj = jf * 16 + fr;
        *(bf16*)((char*)&Ps[wave][ii][0] + ((2 * jj) ^ ((ii & 7) << 4))) =
            (bf16)sf[jf][r];
      }
    __syncthreads();  // forces lgkmcnt(0): Ps writes visible before reads
    // PV: oacc += P * V
#pragma unroll
    for (int s = 0; s < 2; ++s) {
      bf16x8 pa = *(const bf16x8*)((const char*)&Ps[wave][fr][0] +
                   ((s * 64 + fg * 16) ^ ((fr & 7) << 4)));
#pragma unroll
      for (int df = 0; df < 4; ++df) {
        const int vr = df * 16 + fr;
        bf16x8 vb = *(const bf16x8*)((const char*)&Vt[vr][0] +
                     ((s * 64 + fg * 16) ^ ((vr & 7) << 4)));
        oacc[df] = __builtin_amdgcn_mfma_f32_16x16x32_bf16(pa, vb, oacc[df], 0, 0, 0);
      }
    }
  }
  // O = oacc / l
#pragma unroll
  for (int df = 0; df < 4; ++df)
#pragma unroll
    for (int r = 0; r < 4; ++r) {
      const int row = qt * 64 + wave * 16 + fg * 4 + r;
      O[qbase + (size_t)row * DM + df * 16 + fr] = (bf16)(oacc[df][r] / lrow[r]);
    }
}

// ---------------- launch ----------------
extern "C" void kernel_launch(void* const* d_in, const int* in_sizes, int n_in,
                              void* d_out, int out_size, void* d_ws, size_t ws_size,
                              hipStream_t stream) {
  const void* x   = d_in[0];   // [2,2048,1024]  fp32 or bf16
  const void* Wq  = d_in[1];   // [1024,1024]
  const void* Wkv = d_in[2];   // [1024,2048]
  const void* Wo  = d_in[3];   // [1024,1024]

  char* ws = (char*)d_ws;
  int*  flag = (int*)ws;                                   //   4 KiB
  bf16* xb   = (bf16*)(ws + (4ull   << 10));               //   8 MiB [4096][1024]
  bf16* WqT  = (bf16*)(ws + (4ull   << 10) + (8ull  << 20)); // 2 MiB [1024][1024]
  bf16* WkvT = (bf16*)(ws + (4ull   << 10) + (10ull << 20)); // 4 MiB [2048][1024]
  bf16* WoT  = (bf16*)(ws + (4ull   << 10) + (14ull << 20)); // 2 MiB [1024][1024]
  bf16* Qb   = (bf16*)(ws + (4ull   << 10) + (16ull << 20)); // 8 MiB [4096][1024]
  bf16* KVb  = (bf16*)(ws + (4ull   << 10) + (24ull << 20)); //16 MiB [4096][2048]
  bf16* AOb  = xb;  // x dead after in-projections; reuse for attention output

  detect_dtype<<<1, 256, 0, stream>>>((const uint32_t*)x, flag);
  convert_x<<<4194304 / 8 / 256, 256, 0, stream>>>(x, xb, 4194304, flag);

  const dim3 tb(32, 8);
  transpose_conv<<<dim3(1024 / 32, 1024 / 32), tb, 0, stream>>>(Wq,  WqT,  1024, 1024, flag);
  transpose_conv<<<dim3(2048 / 32, 1024 / 32), tb, 0, stream>>>(Wkv, WkvT, 1024, 2048, flag);
  transpose_conv<<<dim3(1024 / 32, 1024 / 32), tb, 0, stream>>>(Wo,  WoT,  1024, 1024, flag);

  gemm_bt<<<dim3(1024 / 128, 4096 / 128), 256, 0, stream>>>(xb, WqT,  Qb,  4096, 1024, 1024, nullptr);
  gemm_bt<<<dim3(2048 / 128, 4096 / 128), 256, 0, stream>>>(xb, WkvT, KVb, 4096, 2048, 1024, nullptr);

  attn_fwd<<<dim3(NSEQ / 64, 32), 256, 0, stream>>>(Qb, KVb, AOb);

  gemm_bt<<<dim3(1024 / 128, 4096 / 128), 256, 0, stream>>>(AOb, WoT, d_out, 4096, 1024, 1024, flag);
}

// Round 3
// 185.831 us; speedup vs baseline: 1.2387x; 1.2387x over previous
//
#include <hip/hip_runtime.h>
#include <stdint.h>
#include <stddef.h>

// Attention_50886772523162: x[2,2048,1024] -> causal MHA (16 heads, hd=64) -> out
// dtype (fp32 vs bf16) detected at runtime; compute bf16 MFMA, fp32 accum.
// Pipeline: detect -> convert x -> transpose weights (Wq|Wkv fused) ->
//           QKV proj (one GEMM) -> swapped-QK^T flash attn -> O proj.

typedef __bf16 bf16;
typedef __bf16 bf16x8 __attribute__((ext_vector_type(8)));
typedef __bf16 bf16x4 __attribute__((ext_vector_type(4)));
typedef __bf16 bf16x2 __attribute__((ext_vector_type(2)));
typedef float  f32x4  __attribute__((ext_vector_type(4)));
typedef float  f32x16 __attribute__((ext_vector_type(16)));

#define NSEQ 2048
#define DM   1024
#define HD   64
#define QKVS 3072          // fused QKV row stride
#define LOG2E 1.44269504f

// ---------------- dtype detection ----------------
__global__ void detect_dtype(const uint32_t* __restrict__ x, int* __restrict__ flag) {
  __shared__ int cnt;
  if (threadIdx.x == 0) cnt = 0;
  __syncthreads();
  int c = 0;
  for (int i = threadIdx.x; i < 4096; i += 256) {
    uint32_t e = (x[i] >> 7) & 0xFF;
    if (e >= 110 && e <= 132) c++;
  }
  atomicAdd(&cnt, c);
  __syncthreads();
  if (threadIdx.x == 0) *flag = (cnt > 2048) ? 1 : 0;   // 1 = bf16 data
}

// ---------------- x -> canonical bf16 ----------------
__global__ __launch_bounds__(256) void convert_x(
    const void* __restrict__ in, bf16* __restrict__ out, int n,
    const int* __restrict__ flagp) {
  const int flag = *flagp;
  const int i = (blockIdx.x * 256 + threadIdx.x) * 8;
  if (i >= n) return;
  if (flag) {
    *(bf16x8*)(out + i) = *(const bf16x8*)((const bf16*)in + i);
  } else {
    const float* f = (const float*)in;
    bf16x8 v;
#pragma unroll
    for (int e = 0; e < 8; ++e) v[e] = (bf16)f[i + e];
    *(bf16x8*)(out + i) = v;
  }
}

// ---------------- weight transpose(+convert): in[K][N] -> out[N][K] ----------------
__global__ void transpose_conv(const void* __restrict__ in, bf16* __restrict__ out,
                               int K, int N, const int* __restrict__ flagp) {
  __shared__ bf16 tile[32][33];
  const int flag = *flagp;
  const int k0 = blockIdx.y * 32, n0 = blockIdx.x * 32;
  const int tx = threadIdx.x, ty = threadIdx.y;
  if (flag) {
    const bf16* p = (const bf16*)in;
#pragma unroll
    for (int i = ty; i < 32; i += 8)
      tile[i][tx] = p[(size_t)(k0 + i) * N + n0 + tx];
  } else {
    const float* p = (const float*)in;
#pragma unroll
    for (int i = ty; i < 32; i += 8)
      tile[i][tx] = (bf16)p[(size_t)(k0 + i) * N + n0 + tx];
  }
  __syncthreads();
#pragma unroll
  for (int i = ty; i < 32; i += 8)
    out[(size_t)(n0 + i) * K + k0 + tx] = tile[tx][i];
}

// ---------------- GEMM: C[M][N] = A[M][K] * Bt[N][K]^T ----------------
__global__ __launch_bounds__(256) void gemm_bt(
    const bf16* __restrict__ A, const bf16* __restrict__ Bt,
    void* __restrict__ C, int M, int N, int K, const int* flagp)
{
  __shared__ bf16 As[128][64];
  __shared__ bf16 Bs[128][64];
  const int tid  = threadIdx.x;
  const int wave = tid >> 6, lane = tid & 63;
  const int fr = lane & 15, fg = lane >> 4;
  const int m0 = blockIdx.y * 128, n0 = blockIdx.x * 128;
  const int wr = (wave >> 1) * 64, wc = (wave & 1) * 64;
  const int srow = tid >> 3, sch = tid & 7;

  f32x4 acc[4][4] = {};

  for (int kt = 0; kt < K; kt += 64) {
    __syncthreads();
#pragma unroll
    for (int p = 0; p < 4; ++p) {
      const int r = srow + p * 32;
      bf16x8 va = *(const bf16x8*)(A  + (size_t)(m0 + r) * K + kt + sch * 8);
      bf16x8 vb = *(const bf16x8*)(Bt + (size_t)(n0 + r) * K + kt + sch * 8);
      const int lb = (sch * 16) ^ ((r & 7) << 4);
      *(bf16x8*)((char*)&As[r][0] + lb) = va;
      *(bf16x8*)((char*)&Bs[r][0] + lb) = vb;
    }
    __syncthreads();
#pragma unroll
    for (int s = 0; s < 2; ++s) {
      bf16x8 af[4], bfr[4];
#pragma unroll
      for (int i = 0; i < 4; ++i) {
        const int ar = wr + i * 16 + fr;
        af[i]  = *(const bf16x8*)((const char*)&As[ar][0] +
                   ((s * 64 + fg * 16) ^ ((ar & 7) << 4)));
        const int br = wc + i * 16 + fr;
        bfr[i] = *(const bf16x8*)((const char*)&Bs[br][0] +
                   ((s * 64 + fg * 16) ^ ((br & 7) << 4)));
      }
#pragma unroll
      for (int i = 0; i < 4; ++i)
#pragma unroll
        for (int j = 0; j < 4; ++j)
          acc[i][j] = __builtin_amdgcn_mfma_f32_16x16x32_bf16(
              af[i], bfr[j], acc[i][j], 0, 0, 0);
    }
  }
  const int crow = m0 + wr + fg * 4;
  const int ccol = n0 + wc + fr;
  const int as_bf16 = flagp ? *flagp : 1;
  if (as_bf16) {
    bf16* Cb = (bf16*)C;
#pragma unroll
    for (int i = 0; i < 4; ++i)
#pragma unroll
      for (int j = 0; j < 4; ++j)
#pragma unroll
        for (int r = 0; r < 4; ++r)
          Cb[(size_t)(crow + i * 16 + r) * N + ccol + j * 16] = (bf16)acc[i][j][r];
  } else {
    float* Cf = (float*)C;
#pragma unroll
    for (int i = 0; i < 4; ++i)
#pragma unroll
      for (int j = 0; j < 4; ++j)
#pragma unroll
        for (int r = 0; r < 4; ++r)
          Cf[(size_t)(crow + i * 16 + r) * N + ccol + j * 16] = acc[i][j][r];
  }
}

// ---------------- causal flash attention, swapped-operand ----------------
// QKV: [B*N][3072] rows = (Q | K | V), head col offset hi*64.
// Block: 4 waves x 32 q-rows = 128 q-rows; KV tiles of 64.
// S^T = mfma(K, Q): lane owns q-row (col=lane&31); softmax lane-local.
// O^T = mfma(V^T, P): output col also = q-row -> rescale/divide lane-local.
static __device__ inline uint32_t pk2(float a, float b) {
  bf16x2 t; t[0] = (bf16)a; t[1] = (bf16)b;
  return __builtin_bit_cast(uint32_t, t);
}

__global__ __launch_bounds__(256) void attn_fwd(
    const bf16* __restrict__ QKV, bf16* __restrict__ O)
{
  __shared__ bf16 Ks[64][64];   // K tile [kv][d], rows XOR-swizzled
  __shared__ bf16 Vt[64][64];   // V tile transposed [d][kv], rows XOR-swizzled

  const int qt = gridDim.x - 1 - blockIdx.x;  // heavy blocks first (LPT)
  const int bh = blockIdx.y;
  const int bi = bh >> 4, hi = bh & 15;
  const int tid = threadIdx.x, wave = tid >> 6, lane = tid & 63;
  const int c = lane & 31, h = lane >> 5;

  const bf16* qptr = QKV + (size_t)bi * NSEQ * QKVS + hi * HD;
  const bf16* kptr = qptr + DM;
  const bf16* vptr = qptr + 2 * DM;

  const int q0w  = qt * 128 + wave * 32;
  const int qrow = q0w + c;

  // Q fragments (B-operand): k = d = ks*16 + h*8 + e
  bf16x8 qf[4];
#pragma unroll
  for (int ks = 0; ks < 4; ++ks)
    qf[ks] = *(const bf16x8*)(qptr + (size_t)qrow * QKVS + ks * 16 + h * 8);

  f32x16 oacc[2] = {};          // O^T: col=q (lane-local), rows d spread
  float m = -1e30f, l = 0.f;

  const int sjr = tid >> 3, sjc = tid & 7;               // K staging
  const int vjp = (tid & 31) * 2, vd0 = (tid >> 5) * 8;  // V transpose staging

  const int ntiles = 2 * qt + 2;
  for (int t = 0; t < ntiles; ++t) {
    const int j0 = t * 64;
    __syncthreads();
    // stage K [64][64]
#pragma unroll
    for (int p = 0; p < 2; ++p) {
      const int j = sjr + p * 32;
      bf16x8 v = *(const bf16x8*)(kptr + (size_t)(j0 + j) * QKVS + sjc * 8);
      *(bf16x8*)((char*)&Ks[j][0] + ((sjc * 16) ^ ((j & 7) << 4))) = v;
    }
    // stage V transposed -> Vt[d][kv]
    {
      bf16x8 v0 = *(const bf16x8*)(vptr + (size_t)(j0 + vjp)     * QKVS + vd0);
      bf16x8 v1 = *(const bf16x8*)(vptr + (size_t)(j0 + vjp + 1) * QKVS + vd0);
#pragma unroll
      for (int e = 0; e < 8; ++e) {
        const int d = vd0 + e;
        bf16x2 pr; pr[0] = v0[e]; pr[1] = v1[e];
        *(bf16x2*)((char*)&Vt[d][0] + ((vjp * 2) ^ ((d & 7) << 4))) = pr;
      }
    }
    __syncthreads();

    if (j0 > q0w + 31) continue;   // fully masked for this wave (uniform)

    // S^T: s[blk][r] = S[q = qrow][kv = j0 + 32*blk + (r&3)+8*(r>>2)+4*h]
    f32x16 s[2];
#pragma unroll
    for (int blk = 0; blk < 2; ++blk) {
      f32x16 a = {};
#pragma unroll
      for (int ks = 0; ks < 4; ++ks) {
        const int krow = blk * 32 + c;
        bf16x8 kf = *(const bf16x8*)((const char*)&Ks[krow][0] +
                     ((ks * 32 + h * 16) ^ ((krow & 7) << 4)));
        a = __builtin_amdgcn_mfma_f32_32x32x16_bf16(kf, qf[ks], a, 0, 0, 0);
      }
      s[blk] = a;
    }

    // causal mask (raw-S domain; -4e8*0.125 = -5e7 ~ exact zero after exp)
    if (j0 + 63 > q0w) {
#pragma unroll
      for (int blk = 0; blk < 2; ++blk) {
        const int kvb = j0 + blk * 32 + 4 * h;
#pragma unroll
        for (int r = 0; r < 16; ++r) {
          const int kv = kvb + (r & 3) + 8 * (r >> 2);
          if (kv > qrow) s[blk][r] = -4.0e8f;
        }
      }
    }

    // online softmax, lane-local (one q-row per lane)
    float tmax = -3.0e38f;
#pragma unroll
    for (int blk = 0; blk < 2; ++blk)
#pragma unroll
      for (int r = 0; r < 16; ++r) tmax = fmaxf(tmax, s[blk][r]);
    tmax = fmaxf(tmax, __shfl_xor(tmax, 32));
    const float mnew  = fmaxf(m, tmax * 0.125f);
    const float alpha = exp2f((m - mnew) * LOG2E);
    m = mnew;
    const float km = 0.125f * LOG2E, kb = -mnew * LOG2E;
    float sum = 0.f;
#pragma unroll
    for (int blk = 0; blk < 2; ++blk)
#pragma unroll
      for (int r = 0; r < 16; ++r) {
        const float p = exp2f(__builtin_fmaf(s[blk][r], km, kb));
        s[blk][r] = p;
        sum += p;
      }
    sum += __shfl_xor(sum, 32);
    l = l * alpha + sum;
#pragma unroll
    for (int db = 0; db < 2; ++db)
#pragma unroll
      for (int r = 0; r < 16; ++r) oacc[db][r] *= alpha;

    // P redistribution (D-layout -> B-operand) + PV
#pragma unroll
    for (int blk = 0; blk < 2; ++blk) {
      uint32_t w[8], xw[8];
#pragma unroll
      for (int g = 0; g < 4; ++g) {
        w[2 * g]     = pk2(s[blk][4 * g],     s[blk][4 * g + 1]);
        w[2 * g + 1] = pk2(s[blk][4 * g + 2], s[blk][4 * g + 3]);
      }
#pragma unroll
      for (int i = 0; i < 8; ++i)
        xw[i] = (uint32_t)__shfl_xor((int)w[i], 32);
#pragma unroll
      for (int ks = 0; ks < 2; ++ks) {
        union { uint32_t u[4]; bf16x8 v; } pf;
        pf.u[0] = h ? xw[4 * ks + 2] : w[4 * ks];
        pf.u[1] = h ? xw[4 * ks + 3] : w[4 * ks + 1];
        pf.u[2] = h ? w[4 * ks + 2]  : xw[4 * ks];
        pf.u[3] = h ? w[4 * ks + 3]  : xw[4 * ks + 1];
#pragma unroll
        for (int db = 0; db < 2; ++db) {
          const int vrow = db * 32 + c;
          bf16x8 vf = *(const bf16x8*)((const char*)&Vt[vrow][0] +
                       ((blk * 64 + ks * 32 + h * 16) ^ ((vrow & 7) << 4)));
          oacc[db] = __builtin_amdgcn_mfma_f32_32x32x16_bf16(vf, pf.v, oacc[db], 0, 0, 0);
        }
      }
    }
  }

  // epilogue: O[q][d] = oacc^T / l   (all lane-local)
  const float linv = 1.f / l;
  bf16* obase = O + (size_t)bi * NSEQ * DM + (size_t)hi * HD + (size_t)qrow * DM;
#pragma unroll
  for (int db = 0; db < 2; ++db)
#pragma unroll
    for (int g = 0; g < 4; ++g) {
      bf16x4 ov;
#pragma unroll
      for (int j = 0; j < 4; ++j) ov[j] = (bf16)(oacc[db][4 * g + j] * linv);
      *(bf16x4*)(obase + db * 32 + 8 * g + 4 * h) = ov;
    }
}

// ---------------- launch ----------------
extern "C" void kernel_launch(void* const* d_in, const int* in_sizes, int n_in,
                              void* d_out, int out_size, void* d_ws, size_t ws_size,
                              hipStream_t stream) {
  const void* x   = d_in[0];   // [2,2048,1024]
  const void* Wq  = d_in[1];   // [1024,1024]
  const void* Wkv = d_in[2];   // [1024,2048]
  const void* Wo  = d_in[3];   // [1024,1024]

  char* ws = (char*)d_ws;
  int*  flag   = (int*)ws;                                      //   4 KiB
  bf16* xb     = (bf16*)(ws + (4ull << 10));                    //   8 MiB
  bf16* WqkvT  = (bf16*)(ws + (4ull << 10) + (8ull  << 20));    //   6 MiB [3072][1024]
  bf16* WoT    = (bf16*)(ws + (4ull << 10) + (14ull << 20));    //   2 MiB [1024][1024]
  bf16* QKVb   = (bf16*)(ws + (4ull << 10) + (16ull << 20));    //  24 MiB [4096][3072]
  bf16* AOb    = xb;  // x dead after projection; reuse

  detect_dtype<<<1, 256, 0, stream>>>((const uint32_t*)x, flag);
  convert_x<<<4194304 / 8 / 256, 256, 0, stream>>>(x, xb, 4194304, flag);

  const dim3 tb(32, 8);
  transpose_conv<<<dim3(1024 / 32, 1024 / 32), tb, 0, stream>>>(Wq,  WqkvT,                1024, 1024, flag);
  transpose_conv<<<dim3(2048 / 32, 1024 / 32), tb, 0, stream>>>(Wkv, WqkvT + 1024 * 1024,  1024, 2048, flag);
  transpose_conv<<<dim3(1024 / 32, 1024 / 32), tb, 0, stream>>>(Wo,  WoT,                  1024, 1024, flag);

  // fused QKV projection: x @ [Wq | Wkv]
  gemm_bt<<<dim3(3072 / 128, 4096 / 128), 256, 0, stream>>>(xb, WqkvT, QKVb, 4096, 3072, 1024, nullptr);

  attn_fwd<<<dim3(16, 32), 256, 0, stream>>>(QKVb, AOb);

  gemm_bt<<<dim3(1024 / 128, 4096 / 128), 256, 0, stream>>>(AOb, WoT, d_out, 4096, 1024, 1024, flag);
}

// Round 4
// 162.574 us; speedup vs baseline: 1.4159x; 1.1431x over previous
//
#include <hip/hip_runtime.h>
#include <stdint.h>
#include <stddef.h>

// Attention_50886772523162: x[2,2048,1024] -> causal MHA (16 heads, hd=64) -> out
// dtype (fp32 vs bf16) detected at runtime; compute bf16 MFMA, fp32 accum.
// Pipeline: detect -> convert x -> transpose weights (Wq|Wkv fused) ->
//           QKV proj (one GEMM, global_load_lds staging) ->
//           swapped-QK^T flash attn (double-buffered, async-STAGE, defer-max) ->
//           O proj.

typedef __bf16 bf16;
typedef __bf16 bf16x8 __attribute__((ext_vector_type(8)));
typedef __bf16 bf16x4 __attribute__((ext_vector_type(4)));
typedef __bf16 bf16x2 __attribute__((ext_vector_type(2)));
typedef float  f32x4  __attribute__((ext_vector_type(4)));
typedef float  f32x16 __attribute__((ext_vector_type(16)));

#define NSEQ 2048
#define DM   1024
#define HD   64
#define QKVS 3072          // fused QKV row stride
#define LOG2E 1.44269504f

#define GLD16(g, l) __builtin_amdgcn_global_load_lds(                         \
    (const __attribute__((address_space(1))) void*)(g),                       \
    (__attribute__((address_space(3))) void*)(l), 16, 0, 0)

// ---------------- dtype detection ----------------
__global__ void detect_dtype(const uint32_t* __restrict__ x, int* __restrict__ flag) {
  __shared__ int cnt;
  if (threadIdx.x == 0) cnt = 0;
  __syncthreads();
  int c = 0;
  for (int i = threadIdx.x; i < 4096; i += 256) {
    uint32_t e = (x[i] >> 7) & 0xFF;
    if (e >= 110 && e <= 132) c++;
  }
  atomicAdd(&cnt, c);
  __syncthreads();
  if (threadIdx.x == 0) *flag = (cnt > 2048) ? 1 : 0;   // 1 = bf16 data
}

// ---------------- x -> canonical bf16 ----------------
__global__ __launch_bounds__(256) void convert_x(
    const void* __restrict__ in, bf16* __restrict__ out, int n,
    const int* __restrict__ flagp) {
  const int flag = *flagp;
  const int i = (blockIdx.x * 256 + threadIdx.x) * 8;
  if (i >= n) return;
  if (flag) {
    *(bf16x8*)(out + i) = *(const bf16x8*)((const bf16*)in + i);
  } else {
    const float* f = (const float*)in;
    bf16x8 v;
#pragma unroll
    for (int e = 0; e < 8; ++e) v[e] = (bf16)f[i + e];
    *(bf16x8*)(out + i) = v;
  }
}

// ---------------- weight transpose(+convert): in[K][N] -> out[N][K] ----------------
__global__ void transpose_conv(const void* __restrict__ in, bf16* __restrict__ out,
                               int K, int N, const int* __restrict__ flagp) {
  __shared__ bf16 tile[32][33];
  const int flag = *flagp;
  const int k0 = blockIdx.y * 32, n0 = blockIdx.x * 32;
  const int tx = threadIdx.x, ty = threadIdx.y;
  if (flag) {
    const bf16* p = (const bf16*)in;
#pragma unroll
    for (int i = ty; i < 32; i += 8)
      tile[i][tx] = p[(size_t)(k0 + i) * N + n0 + tx];
  } else {
    const float* p = (const float*)in;
#pragma unroll
    for (int i = ty; i < 32; i += 8)
      tile[i][tx] = (bf16)p[(size_t)(k0 + i) * N + n0 + tx];
  }
  __syncthreads();
#pragma unroll
  for (int i = ty; i < 32; i += 8)
    out[(size_t)(n0 + i) * K + k0 + tx] = tile[tx][i];
}

// ---------------- GEMM: C[M][N] = A[M][K] * Bt[N][K]^T ----------------
// 128x128 tile, BK=64, 4 waves (2x2), mfma_f32_16x16x32_bf16.
// Staging via global_load_lds (16B/lane, linear LDS dest). Source column is
// pre-swizzled (rule 21) so LDS content matches the XOR-swizzled reads:
// granule g_read = g ^ (row&7)  <=>  source granule (lane&7)^(lane>>3).
__global__ __launch_bounds__(256) void gemm_bt(
    const bf16* __restrict__ A, const bf16* __restrict__ Bt,
    void* __restrict__ C, int M, int N, int K, const int* flagp)
{
  __shared__ bf16 As[128][64];
  __shared__ bf16 Bs[128][64];
  const int tid  = threadIdx.x;
  const int wave = tid >> 6, lane = tid & 63;
  const int fr = lane & 15, fg = lane >> 4;
  const int m0 = blockIdx.y * 128, n0 = blockIdx.x * 128;
  const int wr = (wave >> 1) * 64, wc = (wave & 1) * 64;
  const int lrow = lane >> 3;                    // row within 8-row chunk
  const int lcol = 8 * ((lane & 7) ^ lrow);      // pre-swizzled source col (elems)

  f32x4 acc[4][4] = {};

  for (int kt = 0; kt < K; kt += 64) {
    __syncthreads();                              // protect prev-iter reads
#pragma unroll
    for (int p = 0; p < 4; ++p) {
      const int chunk = wave * 4 + p;             // 8 rows per chunk
      const int r = chunk * 8 + lrow;
      GLD16(A  + (size_t)(m0 + r) * K + kt + lcol, &As[chunk * 8][0]);
      GLD16(Bt + (size_t)(n0 + r) * K + kt + lcol, &Bs[chunk * 8][0]);
    }
    __syncthreads();                              // vmcnt(0) drain + barrier
#pragma unroll
    for (int s = 0; s < 2; ++s) {
      bf16x8 af[4], bfr[4];
#pragma unroll
      for (int i = 0; i < 4; ++i) {
        const int ar = wr + i * 16 + fr;
        af[i]  = *(const bf16x8*)((const char*)&As[ar][0] +
                   ((s * 64 + fg * 16) ^ ((ar & 7) << 4)));
        const int br = wc + i * 16 + fr;
        bfr[i] = *(const bf16x8*)((const char*)&Bs[br][0] +
                   ((s * 64 + fg * 16) ^ ((br & 7) << 4)));
      }
#pragma unroll
      for (int i = 0; i < 4; ++i)
#pragma unroll
        for (int j = 0; j < 4; ++j)
          acc[i][j] = __builtin_amdgcn_mfma_f32_16x16x32_bf16(
              af[i], bfr[j], acc[i][j], 0, 0, 0);
    }
  }
  const int crow = m0 + wr + fg * 4;
  const int ccol = n0 + wc + fr;
  const int as_bf16 = flagp ? *flagp : 1;
  if (as_bf16) {
    bf16* Cb = (bf16*)C;
#pragma unroll
    for (int i = 0; i < 4; ++i)
#pragma unroll
      for (int j = 0; j < 4; ++j)
#pragma unroll
        for (int r = 0; r < 4; ++r)
          Cb[(size_t)(crow + i * 16 + r) * N + ccol + j * 16] = (bf16)acc[i][j][r];
  } else {
    float* Cf = (float*)C;
#pragma unroll
    for (int i = 0; i < 4; ++i)
#pragma unroll
      for (int j = 0; j < 4; ++j)
#pragma unroll
        for (int r = 0; r < 4; ++r)
          Cf[(size_t)(crow + i * 16 + r) * N + ccol + j * 16] = acc[i][j][r];
  }
}

// ---------------- causal flash attention, swapped-operand ----------------
// QKV: [B*N][3072] rows = (Q | K | V), head col offset hi*64.
// Block: 4 waves x 32 q-rows = 128 q-rows; KV tiles of 64.
// S^T = mfma(K, Q): lane owns q-row (col=lane&31); softmax lane-local.
// O^T = mfma(V^T, P): output col also = q-row -> rescale/divide lane-local.
// Double-buffered LDS; tile t+1 global loads issued before tile t compute
// (T14 async-STAGE), LDS writes after compute, ONE barrier per tile.
static __device__ inline uint32_t pk2(float a, float b) {
  bf16x2 t; t[0] = (bf16)a; t[1] = (bf16)b;
  return __builtin_bit_cast(uint32_t, t);
}

__global__ __launch_bounds__(256) void attn_fwd(
    const bf16* __restrict__ QKV, bf16* __restrict__ O)
{
  __shared__ bf16 Ks[2][64][64];   // K tile [kv][d], rows XOR-swizzled
  __shared__ bf16 Vt[2][64][64];   // V tile transposed [d][kv], XOR-swizzled

  const int qt = gridDim.x - 1 - blockIdx.x;  // heavy blocks first (LPT)
  const int bh = blockIdx.y;
  const int bi = bh >> 4, hi = bh & 15;
  const int tid = threadIdx.x, wave = tid >> 6, lane = tid & 63;
  const int c = lane & 31, h = lane >> 5;

  const bf16* qptr = QKV + (size_t)bi * NSEQ * QKVS + hi * HD;
  const bf16* kptr = qptr + DM;
  const bf16* vptr = qptr + 2 * DM;

  const int q0w  = qt * 128 + wave * 32;
  const int qrow = q0w + c;

  // Q fragments (B-operand): k = d = ks*16 + h*8 + e
  bf16x8 qf[4];
#pragma unroll
  for (int ks = 0; ks < 4; ++ks)
    qf[ks] = *(const bf16x8*)(qptr + (size_t)qrow * QKVS + ks * 16 + h * 8);

  f32x16 oacc[2] = {};          // O^T: col=q (lane-local), rows d spread
  float m = -1e30f, l = 0.f;

  const int sjr = tid >> 3, sjc = tid & 7;               // K staging
  const int koff = (sjc * 16) ^ ((sjr & 7) << 4);
  const int vjp = (tid & 31) * 2, vd0 = (tid >> 5) * 8;  // V transpose staging

  bf16x8 kA, kB, vA, vB;         // prefetch registers (issue-early/write-late)

  const int ntiles = 2 * qt + 2;

  // prologue: tile 0 -> regs -> LDS buf 0
  {
    kA = *(const bf16x8*)(kptr + (size_t)(sjr)      * QKVS + sjc * 8);
    kB = *(const bf16x8*)(kptr + (size_t)(sjr + 32) * QKVS + sjc * 8);
    vA = *(const bf16x8*)(vptr + (size_t)(vjp)      * QKVS + vd0);
    vB = *(const bf16x8*)(vptr + (size_t)(vjp + 1)  * QKVS + vd0);
    *(bf16x8*)((char*)&Ks[0][sjr][0]      + koff) = kA;
    *(bf16x8*)((char*)&Ks[0][sjr + 32][0] + koff) = kB;
#pragma unroll
    for (int e = 0; e < 8; ++e) {
      const int d = vd0 + e;
      bf16x2 pr; pr[0] = vA[e]; pr[1] = vB[e];
      *(bf16x2*)((char*)&Vt[0][d][0] + ((vjp * 2) ^ ((d & 7) << 4))) = pr;
    }
  }
  __syncthreads();

  for (int t = 0; t < ntiles; ++t) {
    const int cur = t & 1;
    const int j0 = t * 64;
    const bool pre = (t + 1 < ntiles);
    if (pre) {                    // issue next-tile loads EARLY (hide under compute)
      const int jn = j0 + 64;
      kA = *(const bf16x8*)(kptr + (size_t)(jn + sjr)      * QKVS + sjc * 8);
      kB = *(const bf16x8*)(kptr + (size_t)(jn + sjr + 32) * QKVS + sjc * 8);
      vA = *(const bf16x8*)(vptr + (size_t)(jn + vjp)      * QKVS + vd0);
      vB = *(const bf16x8*)(vptr + (size_t)(jn + vjp + 1)  * QKVS + vd0);
    }

    if (j0 <= q0w + 31) {         // wave-uniform: tile intersects this wave's rows
      // S^T: s[blk][r] = S[q = qrow][kv = j0 + 32*blk + (r&3)+8*(r>>2)+4*h]
      f32x16 s[2];
#pragma unroll
      for (int blk = 0; blk < 2; ++blk) {
        f32x16 a = {};
#pragma unroll
        for (int ks = 0; ks < 4; ++ks) {
          const int krow = blk * 32 + c;
          bf16x8 kf = *(const bf16x8*)((const char*)&Ks[cur][krow][0] +
                       ((ks * 32 + h * 16) ^ ((krow & 7) << 4)));
          a = __builtin_amdgcn_mfma_f32_32x32x16_bf16(kf, qf[ks], a, 0, 0, 0);
        }
        s[blk] = a;
      }

      // causal mask (raw-S domain)
      if (j0 + 63 > q0w) {
#pragma unroll
        for (int blk = 0; blk < 2; ++blk) {
          const int kvb = j0 + blk * 32 + 4 * h;
#pragma unroll
          for (int r = 0; r < 16; ++r) {
            const int kv = kvb + (r & 3) + 8 * (r >> 2);
            if (kv > qrow) s[blk][r] = -4.0e8f;
          }
        }
      }

      // online softmax, lane-local; defer-max (T13, THR=8)
      float tmax = -3.0e38f;
#pragma unroll
      for (int blk = 0; blk < 2; ++blk)
#pragma unroll
        for (int r = 0; r < 16; ++r) tmax = fmaxf(tmax, s[blk][r]);
      tmax = fmaxf(tmax, __shfl_xor(tmax, 32));
      const float pmax = tmax * 0.125f;
      if (!__all(pmax - m <= 8.0f)) {
        const float mnew  = fmaxf(m, pmax);
        const float alpha = __builtin_amdgcn_exp2f((m - mnew) * LOG2E);
        m = mnew;
        l *= alpha;
#pragma unroll
        for (int db = 0; db < 2; ++db)
#pragma unroll
          for (int r = 0; r < 16; ++r) oacc[db][r] *= alpha;
      }
      const float km = 0.125f * LOG2E, kb = -m * LOG2E;
      float sum = 0.f;
#pragma unroll
      for (int blk = 0; blk < 2; ++blk)
#pragma unroll
        for (int r = 0; r < 16; ++r) {
          const float p = __builtin_amdgcn_exp2f(__builtin_fmaf(s[blk][r], km, kb));
          s[blk][r] = p;
          sum += p;
        }
      sum += __shfl_xor(sum, 32);
      l += sum;

      // P redistribution (D-layout -> B-operand) + PV
#pragma unroll
      for (int blk = 0; blk < 2; ++blk) {
        uint32_t w[8], xw[8];
#pragma unroll
        for (int g = 0; g < 4; ++g) {
          w[2 * g]     = pk2(s[blk][4 * g],     s[blk][4 * g + 1]);
          w[2 * g + 1] = pk2(s[blk][4 * g + 2], s[blk][4 * g + 3]);
        }
#pragma unroll
        for (int i = 0; i < 8; ++i)
          xw[i] = (uint32_t)__shfl_xor((int)w[i], 32);
#pragma unroll
        for (int ks = 0; ks < 2; ++ks) {
          union { uint32_t u[4]; bf16x8 v; } pf;
          pf.u[0] = h ? xw[4 * ks + 2] : w[4 * ks];
          pf.u[1] = h ? xw[4 * ks + 3] : w[4 * ks + 1];
          pf.u[2] = h ? w[4 * ks + 2]  : xw[4 * ks];
          pf.u[3] = h ? w[4 * ks + 3]  : xw[4 * ks + 1];
#pragma unroll
          for (int db = 0; db < 2; ++db) {
            const int vrow = db * 32 + c;
            bf16x8 vf = *(const bf16x8*)((const char*)&Vt[cur][vrow][0] +
                         ((blk * 64 + ks * 32 + h * 16) ^ ((vrow & 7) << 4)));
            oacc[db] = __builtin_amdgcn_mfma_f32_32x32x16_bf16(vf, pf.v, oacc[db], 0, 0, 0);
          }
        }
      }
    }

    if (pre) {                    // write-late: regs -> other LDS buffer
      const int nb = cur ^ 1;
      *(bf16x8*)((char*)&Ks[nb][sjr][0]      + koff) = kA;
      *(bf16x8*)((char*)&Ks[nb][sjr + 32][0] + koff) = kB;
#pragma unroll
      for (int e = 0; e < 8; ++e) {
        const int d = vd0 + e;
        bf16x2 pr; pr[0] = vA[e]; pr[1] = vB[e];
        *(bf16x2*)((char*)&Vt[nb][d][0] + ((vjp * 2) ^ ((d & 7) << 4))) = pr;
      }
    }
    __syncthreads();              // single barrier per tile
  }

  // epilogue: O[q][d] = oacc^T / l   (all lane-local)
  const float linv = 1.f / l;
  bf16* obase = O + (size_t)bi * NSEQ * DM + (size_t)hi * HD + (size_t)qrow * DM;
#pragma unroll
  for (int db = 0; db < 2; ++db)
#pragma unroll
    for (int g = 0; g < 4; ++g) {
      bf16x4 ov;
#pragma unroll
      for (int j = 0; j < 4; ++j) ov[j] = (bf16)(oacc[db][4 * g + j] * linv);
      *(bf16x4*)(obase + db * 32 + 8 * g + 4 * h) = ov;
    }
}

// ---------------- launch ----------------
extern "C" void kernel_launch(void* const* d_in, const int* in_sizes, int n_in,
                              void* d_out, int out_size, void* d_ws, size_t ws_size,
                              hipStream_t stream) {
  const void* x   = d_in[0];   // [2,2048,1024]
  const void* Wq  = d_in[1];   // [1024,1024]
  const void* Wkv = d_in[2];   // [1024,2048]
  const void* Wo  = d_in[3];   // [1024,1024]

  char* ws = (char*)d_ws;
  int*  flag   = (int*)ws;                                      //   4 KiB
  bf16* xb     = (bf16*)(ws + (4ull << 10));                    //   8 MiB
  bf16* WqkvT  = (bf16*)(ws + (4ull << 10) + (8ull  << 20));    //   6 MiB [3072][1024]
  bf16* WoT    = (bf16*)(ws + (4ull << 10) + (14ull << 20));    //   2 MiB [1024][1024]
  bf16* QKVb   = (bf16*)(ws + (4ull << 10) + (16ull << 20));    //  24 MiB [4096][3072]
  bf16* AOb    = xb;  // x dead after projection; reuse

  detect_dtype<<<1, 256, 0, stream>>>((const uint32_t*)x, flag);
  convert_x<<<4194304 / 8 / 256, 256, 0, stream>>>(x, xb, 4194304, flag);

  const dim3 tb(32, 8);
  transpose_conv<<<dim3(1024 / 32, 1024 / 32), tb, 0, stream>>>(Wq,  WqkvT,                1024, 1024, flag);
  transpose_conv<<<dim3(2048 / 32, 1024 / 32), tb, 0, stream>>>(Wkv, WqkvT + 1024 * 1024,  1024, 2048, flag);
  transpose_conv<<<dim3(1024 / 32, 1024 / 32), tb, 0, stream>>>(Wo,  WoT,                  1024, 1024, flag);

  // fused QKV projection: x @ [Wq | Wkv]
  gemm_bt<<<dim3(3072 / 128, 4096 / 128), 256, 0, stream>>>(xb, WqkvT, QKVb, 4096, 3072, 1024, nullptr);

  attn_fwd<<<dim3(16, 32), 256, 0, stream>>>(QKVb, AOb);

  gemm_bt<<<dim3(1024 / 128, 4096 / 128), 256, 0, stream>>>(AOb, WoT, d_out, 4096, 1024, 1024, flag);
}

// Round 6
// 155.998 us; speedup vs baseline: 1.4755x; 1.0422x over previous
//
#include <hip/hip_runtime.h>
#include <stdint.h>
#include <stddef.h>

// Attention_50886772523162: x[2,2048,1024] -> causal MHA (16 heads, hd=64) -> out
// dtype (fp32 vs bf16) detected at runtime; compute bf16 MFMA, fp32 accum.
// Pipeline: detect -> convert x -> transpose weights (Wq|Wkv fused) ->
//           QKV proj (one GEMM, global_load_lds staging) ->
//           swapped-QK^T flash attn (write-at-top dbuf, shfl_xor cross-lane,
//           defer-max, setprio) -> O proj.
// NOTE: raw v_permlane32_swap_b32 inline asm caused NaN in a prior build —
// do not reintroduce without the dedicated builtin and a verifying A/B round.

typedef __bf16 bf16;
typedef __bf16 bf16x8 __attribute__((ext_vector_type(8)));
typedef __bf16 bf16x4 __attribute__((ext_vector_type(4)));
typedef __bf16 bf16x2 __attribute__((ext_vector_type(2)));
typedef float  f32x4  __attribute__((ext_vector_type(4)));
typedef float  f32x16 __attribute__((ext_vector_type(16)));

#define NSEQ 2048
#define DM   1024
#define HD   64
#define QKVS 3072          // fused QKV row stride
#define LOG2E 1.44269504f

#define GLD16(g, l) __builtin_amdgcn_global_load_lds(                         \
    (const __attribute__((address_space(1))) void*)(g),                       \
    (__attribute__((address_space(3))) void*)(l), 16, 0, 0)

// ---------------- dtype detection ----------------
__global__ void detect_dtype(const uint32_t* __restrict__ x, int* __restrict__ flag) {
  __shared__ int cnt;
  if (threadIdx.x == 0) cnt = 0;
  __syncthreads();
  int c = 0;
  for (int i = threadIdx.x; i < 4096; i += 256) {
    uint32_t e = (x[i] >> 7) & 0xFF;
    if (e >= 110 && e <= 132) c++;
  }
  atomicAdd(&cnt, c);
  __syncthreads();
  if (threadIdx.x == 0) *flag = (cnt > 2048) ? 1 : 0;   // 1 = bf16 data
}

// ---------------- x -> canonical bf16 ----------------
__global__ __launch_bounds__(256) void convert_x(
    const void* __restrict__ in, bf16* __restrict__ out, int n,
    const int* __restrict__ flagp) {
  const int flag = *flagp;
  const int i = (blockIdx.x * 256 + threadIdx.x) * 8;
  if (i >= n) return;
  if (flag) {
    *(bf16x8*)(out + i) = *(const bf16x8*)((const bf16*)in + i);
  } else {
    const float* f = (const float*)in;
    bf16x8 v;
#pragma unroll
    for (int e = 0; e < 8; ++e) v[e] = (bf16)f[i + e];
    *(bf16x8*)(out + i) = v;
  }
}

// ---------------- weight transpose(+convert): in[K][N] -> out[N][K] ----------------
__global__ void transpose_conv(const void* __restrict__ in, bf16* __restrict__ out,
                               int K, int N, const int* __restrict__ flagp) {
  __shared__ bf16 tile[32][33];
  const int flag = *flagp;
  const int k0 = blockIdx.y * 32, n0 = blockIdx.x * 32;
  const int tx = threadIdx.x, ty = threadIdx.y;
  if (flag) {
    const bf16* p = (const bf16*)in;
#pragma unroll
    for (int i = ty; i < 32; i += 8)
      tile[i][tx] = p[(size_t)(k0 + i) * N + n0 + tx];
  } else {
    const float* p = (const float*)in;
#pragma unroll
    for (int i = ty; i < 32; i += 8)
      tile[i][tx] = (bf16)p[(size_t)(k0 + i) * N + n0 + tx];
  }
  __syncthreads();
#pragma unroll
  for (int i = ty; i < 32; i += 8)
    out[(size_t)(n0 + i) * K + k0 + tx] = tile[tx][i];
}

// ---------------- GEMM: C[M][N] = A[M][K] * Bt[N][K]^T ----------------
// 128x128 tile, BK=64, 4 waves (2x2), mfma_f32_16x16x32_bf16.
// Staging via global_load_lds (16B/lane, linear LDS dest, pre-swizzled source).
__global__ __launch_bounds__(256) void gemm_bt(
    const bf16* __restrict__ A, const bf16* __restrict__ Bt,
    void* __restrict__ C, int M, int N, int K, const int* flagp)
{
  __shared__ bf16 As[128][64];
  __shared__ bf16 Bs[128][64];
  const int tid  = threadIdx.x;
  const int wave = tid >> 6, lane = tid & 63;
  const int fr = lane & 15, fg = lane >> 4;
  const int m0 = blockIdx.y * 128, n0 = blockIdx.x * 128;
  const int wr = (wave >> 1) * 64, wc = (wave & 1) * 64;
  const int lrow = lane >> 3;                    // row within 8-row chunk
  const int lcol = 8 * ((lane & 7) ^ lrow);      // pre-swizzled source col (elems)

  f32x4 acc[4][4] = {};

  for (int kt = 0; kt < K; kt += 64) {
    __syncthreads();                              // protect prev-iter reads
#pragma unroll
    for (int p = 0; p < 4; ++p) {
      const int chunk = wave * 4 + p;             // 8 rows per chunk
      const int r = chunk * 8 + lrow;
      GLD16(A  + (size_t)(m0 + r) * K + kt + lcol, &As[chunk * 8][0]);
      GLD16(Bt + (size_t)(n0 + r) * K + kt + lcol, &Bs[chunk * 8][0]);
    }
    __syncthreads();                              // vmcnt(0) drain + barrier
#pragma unroll
    for (int s = 0; s < 2; ++s) {
      bf16x8 af[4], bfr[4];
#pragma unroll
      for (int i = 0; i < 4; ++i) {
        const int ar = wr + i * 16 + fr;
        af[i]  = *(const bf16x8*)((const char*)&As[ar][0] +
                   ((s * 64 + fg * 16) ^ ((ar & 7) << 4)));
        const int br = wc + i * 16 + fr;
        bfr[i] = *(const bf16x8*)((const char*)&Bs[br][0] +
                   ((s * 64 + fg * 16) ^ ((br & 7) << 4)));
      }
#pragma unroll
      for (int i = 0; i < 4; ++i)
#pragma unroll
        for (int j = 0; j < 4; ++j)
          acc[i][j] = __builtin_amdgcn_mfma_f32_16x16x32_bf16(
              af[i], bfr[j], acc[i][j], 0, 0, 0);
    }
  }
  const int crow = m0 + wr + fg * 4;
  const int ccol = n0 + wc + fr;
  const int as_bf16 = flagp ? *flagp : 1;
  if (as_bf16) {
    bf16* Cb = (bf16*)C;
#pragma unroll
    for (int i = 0; i < 4; ++i)
#pragma unroll
      for (int j = 0; j < 4; ++j)
#pragma unroll
        for (int r = 0; r < 4; ++r)
          Cb[(size_t)(crow + i * 16 + r) * N + ccol + j * 16] = (bf16)acc[i][j][r];
  } else {
    float* Cf = (float*)C;
#pragma unroll
    for (int i = 0; i < 4; ++i)
#pragma unroll
      for (int j = 0; j < 4; ++j)
#pragma unroll
        for (int r = 0; r < 4; ++r)
          Cf[(size_t)(crow + i * 16 + r) * N + ccol + j * 16] = acc[i][j][r];
  }
}

// ---------------- causal flash attention, swapped-operand ----------------
// QKV: [B*N][3072] rows = (Q | K | V), head col offset hi*64.
// Block: 4 waves x 32 q-rows = 128 q-rows; KV tiles of 64.
// S^T = mfma(K, Q): lane owns q-row (col=lane&31); softmax lane-local.
// O^T = mfma(V^T, P): output col also = q-row -> rescale/divide lane-local.
// Schedule per tile t: [publish regs(t+1)->LDS | issue loads(t+2) | compute(t)]
// -> barrier.  The LDS-publish chain overlaps a full compute phase.
static __device__ inline uint32_t pk2(float a, float b) {
  bf16x2 t; t[0] = (bf16)a; t[1] = (bf16)b;
  return __builtin_bit_cast(uint32_t, t);
}

__global__ __launch_bounds__(256) void attn_fwd(
    const bf16* __restrict__ QKV, bf16* __restrict__ O)
{
  __shared__ bf16 Ks[2][64][64];   // K tile [kv][d], rows XOR-swizzled
  __shared__ bf16 Vt[2][64][64];   // V tile transposed [d][kv], XOR-swizzled

  const int qt = gridDim.x - 1 - blockIdx.x;  // heavy blocks first (LPT)
  const int bh = blockIdx.y;
  const int bi = bh >> 4, hi = bh & 15;
  const int tid = threadIdx.x, wave = tid >> 6, lane = tid & 63;
  const int c = lane & 31, h = lane >> 5;

  const bf16* qptr = QKV + (size_t)bi * NSEQ * QKVS + hi * HD;
  const bf16* kptr = qptr + DM;
  const bf16* vptr = qptr + 2 * DM;

  const int q0w  = qt * 128 + wave * 32;
  const int qrow = q0w + c;

  // Q fragments (B-operand): k = d = ks*16 + h*8 + e
  bf16x8 qf[4];
#pragma unroll
  for (int ks = 0; ks < 4; ++ks)
    qf[ks] = *(const bf16x8*)(qptr + (size_t)qrow * QKVS + ks * 16 + h * 8);

  f32x16 oacc[2] = {};          // O^T: col=q (lane-local), rows d spread
  float m = -1e30f, l = 0.f;

  const int sjr = tid >> 3, sjc = tid & 7;               // K staging
  const int koff = (sjc * 16) ^ ((sjr & 7) << 4);
  const int vjp = (tid & 31) * 2, vd0 = (tid >> 5) * 8;  // V transpose staging

  bf16x8 kA, kB, vA, vB;         // prefetch regs (loaded iter t-1, published top of t+1)

  const int ntiles = 2 * qt + 2; // >= 2 always

  // prologue: tile0 -> LDS buf0 directly; tile1 -> regs
  {
    bf16x8 k0 = *(const bf16x8*)(kptr + (size_t)(sjr)      * QKVS + sjc * 8);
    bf16x8 k1 = *(const bf16x8*)(kptr + (size_t)(sjr + 32) * QKVS + sjc * 8);
    bf16x8 v0 = *(const bf16x8*)(vptr + (size_t)(vjp)      * QKVS + vd0);
    bf16x8 v1 = *(const bf16x8*)(vptr + (size_t)(vjp + 1)  * QKVS + vd0);
    *(bf16x8*)((char*)&Ks[0][sjr][0]      + koff) = k0;
    *(bf16x8*)((char*)&Ks[0][sjr + 32][0] + koff) = k1;
#pragma unroll
    for (int e = 0; e < 8; ++e) {
      const int d = vd0 + e;
      bf16x2 pr; pr[0] = v0[e]; pr[1] = v1[e];
      *(bf16x2*)((char*)&Vt[0][d][0] + ((vjp * 2) ^ ((d & 7) << 4))) = pr;
    }
    kA = *(const bf16x8*)(kptr + (size_t)(64 + sjr)      * QKVS + sjc * 8);
    kB = *(const bf16x8*)(kptr + (size_t)(64 + sjr + 32) * QKVS + sjc * 8);
    vA = *(const bf16x8*)(vptr + (size_t)(64 + vjp)      * QKVS + vd0);
    vB = *(const bf16x8*)(vptr + (size_t)(64 + vjp + 1)  * QKVS + vd0);
  }
  __syncthreads();

  for (int t = 0; t < ntiles; ++t) {
    const int cur = t & 1;
    const int j0 = t * 64;

    // top: publish tile t+1 into the other buffer (its readers finished
    // before the barrier that ended iter t-1)
    if (t + 1 < ntiles) {
      const int nb = cur ^ 1;
      *(bf16x8*)((char*)&Ks[nb][sjr][0]      + koff) = kA;
      *(bf16x8*)((char*)&Ks[nb][sjr + 32][0] + koff) = kB;
#pragma unroll
      for (int e = 0; e < 8; ++e) {
        const int d = vd0 + e;
        bf16x2 pr; pr[0] = vA[e]; pr[1] = vB[e];
        *(bf16x2*)((char*)&Vt[nb][d][0] + ((vjp * 2) ^ ((d & 7) << 4))) = pr;
      }
    }
    // issue tile t+2 loads (land during next iteration's compute)
    if (t + 2 < ntiles) {
      const int jn = j0 + 128;
      kA = *(const bf16x8*)(kptr + (size_t)(jn + sjr)      * QKVS + sjc * 8);
      kB = *(const bf16x8*)(kptr + (size_t)(jn + sjr + 32) * QKVS + sjc * 8);
      vA = *(const bf16x8*)(vptr + (size_t)(jn + vjp)      * QKVS + vd0);
      vB = *(const bf16x8*)(vptr + (size_t)(jn + vjp + 1)  * QKVS + vd0);
    }

    if (j0 <= q0w + 31) {         // wave-uniform: tile intersects this wave's rows
      // S^T: s[blk][r] = S[q = qrow][kv = j0 + 32*blk + (r&3)+8*(r>>2)+4*h]
      f32x16 s[2];
      __builtin_amdgcn_s_setprio(1);
#pragma unroll
      for (int blk = 0; blk < 2; ++blk) {
        f32x16 a = {};
#pragma unroll
        for (int ks = 0; ks < 4; ++ks) {
          const int krow = blk * 32 + c;
          bf16x8 kf = *(const bf16x8*)((const char*)&Ks[cur][krow][0] +
                       ((ks * 32 + h * 16) ^ ((krow & 7) << 4)));
          a = __builtin_amdgcn_mfma_f32_32x32x16_bf16(kf, qf[ks], a, 0, 0, 0);
        }
        s[blk] = a;
      }
      __builtin_amdgcn_s_setprio(0);

      // causal mask (raw-S domain)
      if (j0 + 63 > q0w) {
#pragma unroll
        for (int blk = 0; blk < 2; ++blk) {
          const int kvb = j0 + blk * 32 + 4 * h;
#pragma unroll
          for (int r = 0; r < 16; ++r) {
            const int kv = kvb + (r & 3) + 8 * (r >> 2);
            if (kv > qrow) s[blk][r] = -4.0e8f;
          }
        }
      }

      // online softmax, lane-local; defer-max (T13, THR=8)
      float tmax = -3.0e38f;
#pragma unroll
      for (int blk = 0; blk < 2; ++blk)
#pragma unroll
        for (int r = 0; r < 16; ++r) tmax = fmaxf(tmax, s[blk][r]);
      tmax = fmaxf(tmax, __shfl_xor(tmax, 32));
      const float pmax = tmax * 0.125f;
      if (!__all(pmax - m <= 8.0f)) {
        const float mnew  = fmaxf(m, pmax);
        const float alpha = __builtin_amdgcn_exp2f((m - mnew) * LOG2E);
        m = mnew;
        l *= alpha;
#pragma unroll
        for (int db = 0; db < 2; ++db)
#pragma unroll
          for (int r = 0; r < 16; ++r) oacc[db][r] *= alpha;
      }
      const float km = 0.125f * LOG2E, kb = -m * LOG2E;
      float sum = 0.f;
#pragma unroll
      for (int blk = 0; blk < 2; ++blk)
#pragma unroll
        for (int r = 0; r < 16; ++r) {
          const float p = __builtin_amdgcn_exp2f(__builtin_fmaf(s[blk][r], km, kb));
          s[blk][r] = p;
          sum += p;
        }
      sum += __shfl_xor(sum, 32);
      l += sum;

      // P redistribution (D-layout -> B-operand) + PV  [R4-verified shfl form]
#pragma unroll
      for (int blk = 0; blk < 2; ++blk) {
        uint32_t w[8], xw[8];
#pragma unroll
        for (int g = 0; g < 4; ++g) {
          w[2 * g]     = pk2(s[blk][4 * g],     s[blk][4 * g + 1]);
          w[2 * g + 1] = pk2(s[blk][4 * g + 2], s[blk][4 * g + 3]);
        }
#pragma unroll
        for (int i = 0; i < 8; ++i)
          xw[i] = (uint32_t)__shfl_xor((int)w[i], 32);
#pragma unroll
        for (int ks = 0; ks < 2; ++ks) {
          union { uint32_t u[4]; bf16x8 v; } pf;
          pf.u[0] = h ? xw[4 * ks + 2] : w[4 * ks];
          pf.u[1] = h ? xw[4 * ks + 3] : w[4 * ks + 1];
          pf.u[2] = h ? w[4 * ks + 2]  : xw[4 * ks];
          pf.u[3] = h ? w[4 * ks + 3]  : xw[4 * ks + 1];
          __builtin_amdgcn_s_setprio(1);
#pragma unroll
          for (int db = 0; db < 2; ++db) {
            const int vrow = db * 32 + c;
            bf16x8 vf = *(const bf16x8*)((const char*)&Vt[cur][vrow][0] +
                         ((blk * 64 + ks * 32 + h * 16) ^ ((vrow & 7) << 4)));
            oacc[db] = __builtin_amdgcn_mfma_f32_32x32x16_bf16(vf, pf.v, oacc[db], 0, 0, 0);
          }
          __builtin_amdgcn_s_setprio(0);
        }
      }
    }

    __syncthreads();              // single barrier per tile
  }

  // epilogue: O[q][d] = oacc^T / l   (all lane-local)
  const float linv = 1.f / l;
  bf16* obase = O + (size_t)bi * NSEQ * DM + (size_t)hi * HD + (size_t)qrow * DM;
#pragma unroll
  for (int db = 0; db < 2; ++db)
#pragma unroll
    for (int g = 0; g < 4; ++g) {
      bf16x4 ov;
#pragma unroll
      for (int j = 0; j < 4; ++j) ov[j] = (bf16)(oacc[db][4 * g + j] * linv);
      *(bf16x4*)(obase + db * 32 + 8 * g + 4 * h) = ov;
    }
}

// ---------------- launch ----------------
extern "C" void kernel_launch(void* const* d_in, const int* in_sizes, int n_in,
                              void* d_out, int out_size, void* d_ws, size_t ws_size,
                              hipStream_t stream) {
  const void* x   = d_in[0];   // [2,2048,1024]
  const void* Wq  = d_in[1];   // [1024,1024]
  const void* Wkv = d_in[2];   // [1024,2048]
  const void* Wo  = d_in[3];   // [1024,1024]

  char* ws = (char*)d_ws;
  int*  flag   = (int*)ws;                                      //   4 KiB
  bf16* xb     = (bf16*)(ws + (4ull << 10));                    //   8 MiB
  bf16* WqkvT  = (bf16*)(ws + (4ull << 10) + (8ull  << 20));    //   6 MiB [3072][1024]
  bf16* WoT    = (bf16*)(ws + (4ull << 10) + (14ull << 20));    //   2 MiB [1024][1024]
  bf16* QKVb   = (bf16*)(ws + (4ull << 10) + (16ull << 20));    //  24 MiB [4096][3072]
  bf16* AOb    = xb;  // x dead after projection; reuse

  detect_dtype<<<1, 256, 0, stream>>>((const uint32_t*)x, flag);
  convert_x<<<4194304 / 8 / 256, 256, 0, stream>>>(x, xb, 4194304, flag);

  const dim3 tb(32, 8);
  transpose_conv<<<dim3(1024 / 32, 1024 / 32), tb, 0, stream>>>(Wq,  WqkvT,                1024, 1024, flag);
  transpose_conv<<<dim3(2048 / 32, 1024 / 32), tb, 0, stream>>>(Wkv, WqkvT + 1024 * 1024,  1024, 2048, flag);
  transpose_conv<<<dim3(1024 / 32, 1024 / 32), tb, 0, stream>>>(Wo,  WoT,                  1024, 1024, flag);

  // fused QKV projection: x @ [Wq | Wkv]
  gemm_bt<<<dim3(3072 / 128, 4096 / 128), 256, 0, stream>>>(xb, WqkvT, QKVb, 4096, 3072, 1024, nullptr);

  attn_fwd<<<dim3(16, 32), 256, 0, stream>>>(QKVb, AOb);

  gemm_bt<<<dim3(1024 / 128, 4096 / 128), 256, 0, stream>>>(AOb, WoT, d_out, 4096, 1024, 1024, flag);
}